// Round 13
// baseline (187.225 us; speedup 1.0000x reference)
//
#include <hip/hip_runtime.h>
#include <math.h>

// Problem constants
#define R_   1152
#define C_   10
#define D_   16
#define I_   8
#define B_   256
#define N_   160      // C_*D_ (n = c*16+d)
#define K_   9216     // R_*I_ (k = r*8+i)
#define KS_  32       // K-split across blocks
#define KC_  288      // K_/KS_ per block (9 chunks of 32 k = 4 r-rows)

// workspace layout (float offsets); ~19 MB
#define OFF_WSUM  0                      //    92,160  Wsum[r][c][i]
#define OFF_TT    92160                  // 2,949,120  tT[c][b][r]
#define OFF_V     (OFF_TT + 2949120)     //    40,960  v[b][n]
#define OFF_BIJ   (OFF_V + 40960)        //   184,320  bij[r][n]
#define OFF_E     (OFF_BIJ + 184320)     //   184,320  E[r][n] = exp(bij)
#define OFF_NSA   (OFF_E + 184320)       //       160  nsumA
#define OFF_NSB   (OFF_NSA + 160)        //       160  nsumB
#define OFF_PART  (OFF_NSB + 160)        // 1,310,720  partials[ks][b][n]

// ---------------------------------------------------------------------------
// GEMM: partials[ks][b*160+n] = sum_{k slice} u[b][k] * W[r][n][i] * cw
//   cw = E[r][n]/nsum[n] (HASE) else 1.
// R12 structure with the b-dimension split doubled: 32 bt x 32 ks = 1024
// blocks = 4 blocks/CU (was 512 = 2/CU, the latency-hiding bottleneck).
// Per-lane tile 2b x 10n; 20 KB LDS (staging quarters double as the epilogue
// reduce arena); __launch_bounds__(256,4) pins 4 waves/SIMD.
// bt in LOW bits: the 32 blocks sharing one W k-slice are dispatch-adjacent.
// When !HASE, extra blocks [1024,1384) compute Wsum; block 0 zeros nsums.
template <int HASE>
__launch_bounds__(256, 4)
__global__ void gemm_kernel(const float* __restrict__ u, const float* __restrict__ W,
                            const float* __restrict__ E, const float* __restrict__ nsum,
                            float* __restrict__ partials, float* __restrict__ Wsum,
                            float* __restrict__ zA, float* __restrict__ zB) {
    int tid = threadIdx.x;
    if (!HASE && blockIdx.x >= 1024) {                 // fused Wsum pass
        int idx = (blockIdx.x - 1024) * 256 + tid;     // 360 blocks -> 92160 exact
        int r = idx / (C_ * I_);
        int rem = idx % (C_ * I_);
        int c = rem / I_;
        int i = rem % I_;
        const float* p = W + (size_t)r * (C_ * D_ * I_) + c * (D_ * I_) + i;
        float s = 0.0f;
#pragma unroll
        for (int d = 0; d < D_; ++d) s += p[d * I_];
        Wsum[idx] = s;
        return;
    }

    __shared__ float smem[5120];    // 20 KB: 4 wave-quarters; epilogue reduce reuses them
    int wave = tid >> 6, lane = tid & 63;
    int ng = lane & 15, bg = lane >> 4;
    int bt = blockIdx.x & 31, ks = blockIdx.x >> 5;    // 32 bt x 32 ks
    int b0 = bt * 8;
    int n0 = ng * 10;

    if (!HASE && blockIdx.x == 0 && tid < N_) { zA[tid] = 0.0f; zB[tid] = 0.0f; }

    float acc[2][10];
#pragma unroll
    for (int m = 0; m < 2; ++m)
#pragma unroll
        for (int j = 0; j < 10; ++j) acc[m][j] = 0.0f;

    const float* ur[2];
#pragma unroll
    for (int m = 0; m < 2; ++m) ur[m] = u + (size_t)(b0 + bg * 2 + m) * K_;

    // prefetch chunk 0: idx = it*64+lane in [0,320); n = idx>>1; i-half = (idx&1)*4
    float4 wr[5];
    float  ee[5];
    {
        int r = ks * 36 + wave;
#pragma unroll
        for (int it = 0; it < 5; ++it) {
            int idx = it * 64 + lane;
            wr[it] = *(const float4*)(W + (size_t)r * 1280 + idx * 4);
            if (HASE) {
                int n = idx >> 1;
                ee[it] = E[r * N_ + n] / nsum[n];
            }
        }
    }

    int ldsbase = wave * 1280;
    for (int c = 0; c < 9; ++c) {
        // stage chunk c into private wave quarter (transpose i into rows)
#pragma unroll
        for (int it = 0; it < 5; ++it) {
            int idx = it * 64 + lane;
            int n = idx >> 1, ih = (idx & 1) * 4;
            float e = HASE ? ee[it] : 1.0f;
            float* q = &smem[ldsbase + ih * 160 + n];
            q[0]   = wr[it].x * e;
            q[160] = wr[it].y * e;
            q[320] = wr[it].z * e;
            q[480] = wr[it].w * e;
        }
        // prefetch chunk c+1 (clamped refetch keeps pipeline uniform)
        {
            int cn = (c + 1 < 9) ? (c + 1) : 0;
            int r = ks * 36 + cn * 4 + wave;
#pragma unroll
            for (int it = 0; it < 5; ++it) {
                int idx = it * 64 + lane;
                wr[it] = *(const float4*)(W + (size_t)r * 1280 + idx * 4);
                if (HASE) {
                    int n = idx >> 1;
                    ee[it] = E[r * N_ + n] / nsum[n];
                }
            }
        }
        // compute chunk c
#pragma unroll
        for (int g = 0; g < 2; ++g) {
            int kabs = ks * KC_ + c * 32 + wave * 8 + g * 4;
            float ua[2][4];
#pragma unroll
            for (int m = 0; m < 2; ++m) {
                float4 tmp = *(const float4*)(ur[m] + kabs);
                ua[m][0] = tmp.x; ua[m][1] = tmp.y; ua[m][2] = tmp.z; ua[m][3] = tmp.w;
            }
#pragma unroll
            for (int t4 = 0; t4 < 4; ++t4) {
                const float* wrow = &smem[ldsbase + (g * 4 + t4) * 160 + n0];
                float w[10];
#pragma unroll
                for (int j = 0; j < 10; j += 2) {
                    float2 ww = *(const float2*)(wrow + j);
                    w[j] = ww.x; w[j + 1] = ww.y;
                }
#pragma unroll
                for (int m = 0; m < 2; ++m)
#pragma unroll
                    for (int j = 0; j < 10; ++j)
                        acc[m][j] = fmaf(ua[m][t4], w[j], acc[m][j]);
            }
        }
    }

    // epilogue: cross-wave reduce in the (now free) staging quarters
    __syncthreads();
#pragma unroll
    for (int m = 0; m < 2; ++m)
#pragma unroll
        for (int j = 0; j < 10; ++j)
            smem[wave * 1280 + (bg * 2 + m) * N_ + n0 + j] = acc[m][j];
    __syncthreads();
    float* outp = partials + (size_t)ks * (B_ * N_) + (size_t)b0 * N_;
#pragma unroll
    for (int z = 0; z < 5; ++z) {
        int f = tid + z * 256;                         // 1280 exact
        outp[f] = smem[f] + smem[1280 + f] + smem[2560 + f] + smem[3840 + f];
    }
}

// ---------------------------------------------------------------------------
// rsv: blocks [0,160): dst[g] = squash(scale * sum_ks partials[ks][g])
//      blocks [160,520) (DOT only): tT[c][b][r] = sum_i Wsum[r,c,i]*u[b,r,i]
template <int DOT>
__global__ void rsv_kernel(const float* __restrict__ partials, float* __restrict__ dst,
                           float scale, const float* __restrict__ u,
                           const float* __restrict__ Wsum, float* __restrict__ tT) {
    int tid = threadIdx.x;
    if (DOT && blockIdx.x >= 160) {                    // fused t-pass
        for (int idx = (blockIdx.x - 160) * 256 + tid; idx < B_ * R_; idx += 360 * 256) {
            int r = idx % R_;
            int b = idx / R_;
            const float4* up = (const float4*)(u + (size_t)idx * I_);
            float4 a0 = up[0], a1 = up[1];
            const float* wp = Wsum + (size_t)r * (C_ * I_);
            float outv[C_];
#pragma unroll
            for (int c = 0; c < C_; ++c) {
                const float4* w4 = (const float4*)(wp + c * I_);
                float4 w0 = w4[0], w1 = w4[1];
                outv[c] = a0.x * w0.x + a0.y * w0.y + a0.z * w0.z + a0.w * w0.w
                        + a1.x * w1.x + a1.y * w1.y + a1.z * w1.z + a1.w * w1.w;
            }
#pragma unroll
            for (int c = 0; c < C_; ++c)
                tT[((size_t)c * B_ + b) * R_ + r] = outv[c];   // coalesced in r
        }
        return;
    }
    int g = blockIdx.x * 256 + tid;                    // 40960 exact
    float s = 0.0f;
#pragma unroll
    for (int ks = 0; ks < KS_; ++ks) s += partials[(size_t)ks * (B_ * N_) + g];
    s *= scale;
    float sq = s * s;
    dst[g] = sq / (1.0f + sq) * s / (sqrtf(sq) + 1e-5f);
}

// ---------------------------------------------------------------------------
// bupd: per block (c, r0-tile of 64):
//   bij[r][n] (+)= (1/B) sum_b v[b][n] * tT[c][b][r]
//   E[r][n] = exp(bij); nsum[n] += sum_r E   (max-free softmax)
__launch_bounds__(256)
__global__ void bupd_kernel(const float* __restrict__ v, const float* __restrict__ tT,
                            float* __restrict__ bij, float* __restrict__ E,
                            float* __restrict__ nsum, int accumulate) {
    __shared__ float vs[B_ * 16];     // [b][d] 16 KB
    __shared__ float red[16 * 256];   // [d][tid] 16 KB
    int tid = threadIdx.x;
    int c = blockIdx.x % 10;
    int r0 = (blockIdx.x / 10) * 64;
    int rsub = tid & 63, bs = tid >> 6;

    for (int q = tid; q < 1024; q += 256) {
        int b = q >> 2, d4 = q & 3;
        ((float4*)vs)[q] = *(const float4*)(v + (size_t)b * N_ + c * 16 + d4 * 4);
    }
    __syncthreads();

    float acc[16];
#pragma unroll
    for (int d = 0; d < 16; ++d) acc[d] = 0.0f;

    const float* tp = tT + ((size_t)c * B_ + bs * 64) * R_ + r0 + rsub;
    for (int bb = 0; bb < 64; ++bb) {
        float tv = tp[(size_t)bb * R_];                     // coalesced across wave
        const float4* vrow = (const float4*)(vs + (bs * 64 + bb) * 16); // uniform bcast
        float4 v0 = vrow[0], v1 = vrow[1], v2 = vrow[2], v3 = vrow[3];
        acc[0]  = fmaf(tv, v0.x, acc[0]);  acc[1]  = fmaf(tv, v0.y, acc[1]);
        acc[2]  = fmaf(tv, v0.z, acc[2]);  acc[3]  = fmaf(tv, v0.w, acc[3]);
        acc[4]  = fmaf(tv, v1.x, acc[4]);  acc[5]  = fmaf(tv, v1.y, acc[5]);
        acc[6]  = fmaf(tv, v1.z, acc[6]);  acc[7]  = fmaf(tv, v1.w, acc[7]);
        acc[8]  = fmaf(tv, v2.x, acc[8]);  acc[9]  = fmaf(tv, v2.y, acc[9]);
        acc[10] = fmaf(tv, v2.z, acc[10]); acc[11] = fmaf(tv, v2.w, acc[11]);
        acc[12] = fmaf(tv, v3.x, acc[12]); acc[13] = fmaf(tv, v3.y, acc[13]);
        acc[14] = fmaf(tv, v3.z, acc[14]); acc[15] = fmaf(tv, v3.w, acc[15]);
    }
#pragma unroll
    for (int d = 0; d < 16; ++d) red[d * 256 + tid] = acc[d];
    __syncthreads();

#pragma unroll
    for (int j = 0; j < 4; ++j) {
        int q = tid + 256 * j;
        int rr = q & 63, d = q >> 6;                   // d uniform per wave
        const float* rp = red + d * 256 + rr;
        float s = (rp[0] + rp[64] + rp[128] + rp[192]) * (1.0f / B_);
        int o = (r0 + rr) * N_ + c * 16 + d;
        if (accumulate) s += bij[o];
        bij[o] = s;
        float ex = __expf(s);                          // max-free: |bij| = O(1)
        E[o] = ex;
#pragma unroll
        for (int off = 32; off > 0; off >>= 1) ex += __shfl_down(ex, off, 64);
        if (rr == 0) atomicAdd(&nsum[c * 16 + d], ex);
    }
}

// ---------------------------------------------------------------------------
extern "C" void kernel_launch(void* const* d_in, const int* in_sizes, int n_in,
                              void* d_out, int out_size, void* d_ws, size_t ws_size,
                              hipStream_t stream) {
    (void)in_sizes; (void)n_in; (void)out_size; (void)ws_size;
    const float* u = (const float*)d_in[0];
    const float* W = (const float*)d_in[1];
    float* out = (float*)d_out;
    float* ws = (float*)d_ws;

    float* Wsum     = ws + OFF_WSUM;
    float* tT       = ws + OFF_TT;
    float* v        = ws + OFF_V;
    float* bij      = ws + OFF_BIJ;
    float* E        = ws + OFF_E;
    float* nsumA    = ws + OFF_NSA;
    float* nsumB    = ws + OFF_NSB;
    float* partials = ws + OFF_PART;

    // 8 dispatches
    gemm_kernel<0><<<1384, 256, 0, stream>>>(u, W, nullptr, nullptr, partials,
                                             Wsum, nsumA, nsumB);
    rsv_kernel<1><<<520, 256, 0, stream>>>(partials, v, 1.0f / 1152.0f, u, Wsum, tT);
    bupd_kernel<<<180, 256, 0, stream>>>(v, tT, bij, E, nsumA, 0);

    gemm_kernel<1><<<1024, 256, 0, stream>>>(u, W, E, nsumA, partials,
                                             nullptr, nullptr, nullptr);
    rsv_kernel<0><<<160, 256, 0, stream>>>(partials, v, 1.0f, nullptr, nullptr, nullptr);
    bupd_kernel<<<180, 256, 0, stream>>>(v, tT, bij, E, nsumB, 1);

    gemm_kernel<1><<<1024, 256, 0, stream>>>(u, W, E, nsumB, partials,
                                             nullptr, nullptr, nullptr);
    rsv_kernel<0><<<160, 256, 0, stream>>>(partials, out, 1.0f, nullptr, nullptr, nullptr);
}

// Round 14
// 171.219 us; speedup vs baseline: 1.0935x; 1.0935x over previous
//
#include <hip/hip_runtime.h>
#include <math.h>

// Problem constants
#define R_   1152
#define C_   10
#define D_   16
#define I_   8
#define B_   256
#define N_   160      // C_*D_ (n = c*16+d)
#define K_   9216     // R_*I_ (k = r*8+i)
#define KS_  32       // K-split across blocks
#define KC_  288      // K_/KS_ per block (9 chunks of 32 k = 4 r-rows)

// workspace layout (float offsets); ~19 MB
#define OFF_WSUM  0                      //    92,160  Wsum[r][c][i]
#define OFF_TT    92160                  // 2,949,120  tT[c][b][r]
#define OFF_V     (OFF_TT + 2949120)     //    40,960  v[b][n]
#define OFF_BIJ   (OFF_V + 40960)        //   184,320  bij[r][n]
#define OFF_E     (OFF_BIJ + 184320)     //   184,320  E[r][n] = exp(bij)
#define OFF_NSA   (OFF_E + 184320)       //       160  nsumA
#define OFF_NSB   (OFF_NSA + 160)        //       160  nsumB
#define OFF_PART  (OFF_NSB + 160)        // 1,310,720  partials[ks][b][n]

// ---------------------------------------------------------------------------
// GEMM: partials[ks][b*160+n] = sum_{k slice} u[b][k] * W[r][n][i] * cw
//   cw = E[r][n]/nsum[n] (HASE) else 1.
// R12 structure (best: 178.6 us): 16 bt x 32 ks = 512 blocks, bt in LOW bits
// so W-slice sharers are dispatch-adjacent; barrier-free pipelined K-loop with
// private per-wave LDS quarters. R13 fix: the last-iteration prefetch was a
// DEAD clamped refetch of chunk 0 (~10.5 MB/gemm of cold HBM waste) — now
// guarded with a wave-uniform branch.
// When !HASE, extra blocks [512,872) compute Wsum; block 0 zeros nsums.
template <int HASE>
__launch_bounds__(256)
__global__ void gemm_kernel(const float* __restrict__ u, const float* __restrict__ W,
                            const float* __restrict__ E, const float* __restrict__ nsum,
                            float* __restrict__ partials, float* __restrict__ Wsum,
                            float* __restrict__ zA, float* __restrict__ zB) {
    int tid = threadIdx.x;
    if (!HASE && blockIdx.x >= 512) {                  // fused Wsum pass
        int idx = (blockIdx.x - 512) * 256 + tid;      // 360 blocks -> 92160 exact
        int r = idx / (C_ * I_);
        int rem = idx % (C_ * I_);
        int c = rem / I_;
        int i = rem % I_;
        const float* p = W + (size_t)r * (C_ * D_ * I_) + c * (D_ * I_) + i;
        float s = 0.0f;
#pragma unroll
        for (int d = 0; d < D_; ++d) s += p[d * I_];
        Wsum[idx] = s;
        return;
    }

    __shared__ float smem[10240];   // 40 KB: [0,5120) = 4 wave-quarters; reduce reuses all
    int wave = tid >> 6, lane = tid & 63;
    int ng = lane & 15, bg = lane >> 4;
    int bt = blockIdx.x & 15, ks = blockIdx.x >> 4;    // bt in LOW bits: W-sharers adjacent
    int b0 = bt * 16;
    int n0 = ng * 10;

    if (!HASE && blockIdx.x == 0 && tid < N_) { zA[tid] = 0.0f; zB[tid] = 0.0f; }

    float acc[4][10];
#pragma unroll
    for (int m = 0; m < 4; ++m)
#pragma unroll
        for (int j = 0; j < 10; ++j) acc[m][j] = 0.0f;

    const float* ur[4];
#pragma unroll
    for (int m = 0; m < 4; ++m) ur[m] = u + (size_t)(b0 + bg * 4 + m) * K_;

    // prefetch chunk 0: idx = it*64+lane in [0,320); n = idx>>1; i-half = (idx&1)*4
    float4 wr[5];
    float  ee[5];
    {
        int r = ks * 36 + wave;
#pragma unroll
        for (int it = 0; it < 5; ++it) {
            int idx = it * 64 + lane;
            wr[it] = *(const float4*)(W + (size_t)r * 1280 + idx * 4);
            if (HASE) {
                int n = idx >> 1;
                ee[it] = E[r * N_ + n] / nsum[n];
            }
        }
    }

    int ldsbase = wave * 1280;
    for (int c = 0; c < 9; ++c) {
        // stage chunk c into private wave quarter (transpose i into rows)
#pragma unroll
        for (int it = 0; it < 5; ++it) {
            int idx = it * 64 + lane;
            int n = idx >> 1, ih = (idx & 1) * 4;
            float e = HASE ? ee[it] : 1.0f;
            float* q = &smem[ldsbase + ih * 160 + n];
            q[0]   = wr[it].x * e;
            q[160] = wr[it].y * e;
            q[320] = wr[it].z * e;
            q[480] = wr[it].w * e;
        }
        // prefetch chunk c+1 — guarded: no dead refetch on the last iteration
        if (c < 8) {
            int r = ks * 36 + (c + 1) * 4 + wave;
#pragma unroll
            for (int it = 0; it < 5; ++it) {
                int idx = it * 64 + lane;
                wr[it] = *(const float4*)(W + (size_t)r * 1280 + idx * 4);
                if (HASE) {
                    int n = idx >> 1;
                    ee[it] = E[r * N_ + n] / nsum[n];
                }
            }
        }
        // compute chunk c
#pragma unroll
        for (int g = 0; g < 2; ++g) {
            int kabs = ks * KC_ + c * 32 + wave * 8 + g * 4;
            float ua[4][4];
#pragma unroll
            for (int m = 0; m < 4; ++m) {
                float4 tmp = *(const float4*)(ur[m] + kabs);
                ua[m][0] = tmp.x; ua[m][1] = tmp.y; ua[m][2] = tmp.z; ua[m][3] = tmp.w;
            }
#pragma unroll
            for (int t4 = 0; t4 < 4; ++t4) {
                const float* wrow = &smem[ldsbase + (g * 4 + t4) * 160 + n0];
                float w[10];
#pragma unroll
                for (int j = 0; j < 10; j += 2) {
                    float2 ww = *(const float2*)(wrow + j);
                    w[j] = ww.x; w[j + 1] = ww.y;
                }
#pragma unroll
                for (int m = 0; m < 4; ++m)
#pragma unroll
                    for (int j = 0; j < 10; ++j)
                        acc[m][j] = fmaf(ua[m][t4], w[j], acc[m][j]);
            }
        }
    }

    // epilogue: cross-wave reduce
    __syncthreads();
#pragma unroll
    for (int m = 0; m < 4; ++m)
#pragma unroll
        for (int j = 0; j < 10; ++j)
            smem[wave * 2560 + (bg * 4 + m) * N_ + n0 + j] = acc[m][j];
    __syncthreads();
    float* outp = partials + (size_t)ks * (B_ * N_) + (size_t)b0 * N_;
    for (int f = tid; f < 2560; f += 256)
        outp[f] = smem[f] + smem[2560 + f] + smem[5120 + f] + smem[7680 + f];
}

// ---------------------------------------------------------------------------
// rsv: blocks [0,160): dst[g] = squash(scale * sum_ks partials[ks][g])
//      blocks [160,520) (DOT only): tT[c][b][r] = sum_i Wsum[r,c,i]*u[b,r,i]
template <int DOT>
__global__ void rsv_kernel(const float* __restrict__ partials, float* __restrict__ dst,
                           float scale, const float* __restrict__ u,
                           const float* __restrict__ Wsum, float* __restrict__ tT) {
    int tid = threadIdx.x;
    if (DOT && blockIdx.x >= 160) {                    // fused t-pass
        for (int idx = (blockIdx.x - 160) * 256 + tid; idx < B_ * R_; idx += 360 * 256) {
            int r = idx % R_;
            int b = idx / R_;
            const float4* up = (const float4*)(u + (size_t)idx * I_);
            float4 a0 = up[0], a1 = up[1];
            const float* wp = Wsum + (size_t)r * (C_ * I_);
            float outv[C_];
#pragma unroll
            for (int c = 0; c < C_; ++c) {
                const float4* w4 = (const float4*)(wp + c * I_);
                float4 w0 = w4[0], w1 = w4[1];
                outv[c] = a0.x * w0.x + a0.y * w0.y + a0.z * w0.z + a0.w * w0.w
                        + a1.x * w1.x + a1.y * w1.y + a1.z * w1.z + a1.w * w1.w;
            }
#pragma unroll
            for (int c = 0; c < C_; ++c)
                tT[((size_t)c * B_ + b) * R_ + r] = outv[c];   // coalesced in r
        }
        return;
    }
    int g = blockIdx.x * 256 + tid;                    // 40960 exact
    float s = 0.0f;
#pragma unroll
    for (int ks = 0; ks < KS_; ++ks) s += partials[(size_t)ks * (B_ * N_) + g];
    s *= scale;
    float sq = s * s;
    dst[g] = sq / (1.0f + sq) * s / (sqrtf(sq) + 1e-5f);
}

// ---------------------------------------------------------------------------
// bupd: per block (c, r0-tile of 64):
//   bij[r][n] (+)= (1/B) sum_b v[b][n] * tT[c][b][r]
//   E[r][n] = exp(bij); nsum[n] += sum_r E   (max-free softmax)
__launch_bounds__(256)
__global__ void bupd_kernel(const float* __restrict__ v, const float* __restrict__ tT,
                            float* __restrict__ bij, float* __restrict__ E,
                            float* __restrict__ nsum, int accumulate) {
    __shared__ float vs[B_ * 16];     // [b][d] 16 KB
    __shared__ float red[16 * 256];   // [d][tid] 16 KB
    int tid = threadIdx.x;
    int c = blockIdx.x % 10;
    int r0 = (blockIdx.x / 10) * 64;
    int rsub = tid & 63, bs = tid >> 6;

    for (int q = tid; q < 1024; q += 256) {
        int b = q >> 2, d4 = q & 3;
        ((float4*)vs)[q] = *(const float4*)(v + (size_t)b * N_ + c * 16 + d4 * 4);
    }
    __syncthreads();

    float acc[16];
#pragma unroll
    for (int d = 0; d < 16; ++d) acc[d] = 0.0f;

    const float* tp = tT + ((size_t)c * B_ + bs * 64) * R_ + r0 + rsub;
    for (int bb = 0; bb < 64; ++bb) {
        float tv = tp[(size_t)bb * R_];                     // coalesced across wave
        const float4* vrow = (const float4*)(vs + (bs * 64 + bb) * 16); // uniform bcast
        float4 v0 = vrow[0], v1 = vrow[1], v2 = vrow[2], v3 = vrow[3];
        acc[0]  = fmaf(tv, v0.x, acc[0]);  acc[1]  = fmaf(tv, v0.y, acc[1]);
        acc[2]  = fmaf(tv, v0.z, acc[2]);  acc[3]  = fmaf(tv, v0.w, acc[3]);
        acc[4]  = fmaf(tv, v1.x, acc[4]);  acc[5]  = fmaf(tv, v1.y, acc[5]);
        acc[6]  = fmaf(tv, v1.z, acc[6]);  acc[7]  = fmaf(tv, v1.w, acc[7]);
        acc[8]  = fmaf(tv, v2.x, acc[8]);  acc[9]  = fmaf(tv, v2.y, acc[9]);
        acc[10] = fmaf(tv, v2.z, acc[10]); acc[11] = fmaf(tv, v2.w, acc[11]);
        acc[12] = fmaf(tv, v3.x, acc[12]); acc[13] = fmaf(tv, v3.y, acc[13]);
        acc[14] = fmaf(tv, v3.z, acc[14]); acc[15] = fmaf(tv, v3.w, acc[15]);
    }
#pragma unroll
    for (int d = 0; d < 16; ++d) red[d * 256 + tid] = acc[d];
    __syncthreads();

#pragma unroll
    for (int j = 0; j < 4; ++j) {
        int q = tid + 256 * j;
        int rr = q & 63, d = q >> 6;                   // d uniform per wave
        const float* rp = red + d * 256 + rr;
        float s = (rp[0] + rp[64] + rp[128] + rp[192]) * (1.0f / B_);
        int o = (r0 + rr) * N_ + c * 16 + d;
        if (accumulate) s += bij[o];
        bij[o] = s;
        float ex = __expf(s);                          // max-free: |bij| = O(1)
        E[o] = ex;
#pragma unroll
        for (int off = 32; off > 0; off >>= 1) ex += __shfl_down(ex, off, 64);
        if (rr == 0) atomicAdd(&nsum[c * 16 + d], ex);
    }
}

// ---------------------------------------------------------------------------
extern "C" void kernel_launch(void* const* d_in, const int* in_sizes, int n_in,
                              void* d_out, int out_size, void* d_ws, size_t ws_size,
                              hipStream_t stream) {
    (void)in_sizes; (void)n_in; (void)out_size; (void)ws_size;
    const float* u = (const float*)d_in[0];
    const float* W = (const float*)d_in[1];
    float* out = (float*)d_out;
    float* ws = (float*)d_ws;

    float* Wsum     = ws + OFF_WSUM;
    float* tT       = ws + OFF_TT;
    float* v        = ws + OFF_V;
    float* bij      = ws + OFF_BIJ;
    float* E        = ws + OFF_E;
    float* nsumA    = ws + OFF_NSA;
    float* nsumB    = ws + OFF_NSB;
    float* partials = ws + OFF_PART;

    // 8 dispatches
    gemm_kernel<0><<<872, 256, 0, stream>>>(u, W, nullptr, nullptr, partials,
                                            Wsum, nsumA, nsumB);
    rsv_kernel<1><<<520, 256, 0, stream>>>(partials, v, 1.0f / 1152.0f, u, Wsum, tT);
    bupd_kernel<<<180, 256, 0, stream>>>(v, tT, bij, E, nsumA, 0);

    gemm_kernel<1><<<512, 256, 0, stream>>>(u, W, E, nsumA, partials,
                                            nullptr, nullptr, nullptr);
    rsv_kernel<0><<<160, 256, 0, stream>>>(partials, v, 1.0f, nullptr, nullptr, nullptr);
    bupd_kernel<<<180, 256, 0, stream>>>(v, tT, bij, E, nsumB, 1);

    gemm_kernel<1><<<512, 256, 0, stream>>>(u, W, E, nsumB, partials,
                                            nullptr, nullptr, nullptr);
    rsv_kernel<0><<<160, 256, 0, stream>>>(partials, out, 1.0f, nullptr, nullptr, nullptr);
}